// Round 1
// baseline (579.068 us; speedup 1.0000x reference)
//
#include <hip/hip_runtime.h>
#include <hip/hip_bf16.h>

// SDPA: B=2,H=16,S=2048,DK=DV=64, fp32 in/out, additive mask (1,1,S,S).
// Flash-attention, bf16 MFMA 16x16x32, fp32 accum.
// Per wave: 32 q-rows (2 subtiles of 16). 4 waves/block, no LDS/syncs.

constexpr int Bn = 2, Hn = 16, Sn = 2048, DKn = 64, DVn = 64;
constexpr int QSUB = 2;               // 16-row q-subtiles per wave
constexpr int WAVES = 4;
constexpr int QB = WAVES * QSUB * 16; // 128 q rows per workgroup
constexpr float SCALE = 0.125f;       // 1/sqrt(64)

typedef __attribute__((ext_vector_type(8))) short bf16x8;
typedef __attribute__((ext_vector_type(4))) float f32x4;

union Frag {
  bf16x8 v;
  unsigned short s[8];
  unsigned int u[4];
};

__device__ __forceinline__ unsigned short f2bf(float x) {
  union { float f; unsigned u; } c; c.f = x;
  unsigned r = c.u + 0x7FFFu + ((c.u >> 16) & 1u);
  return (unsigned short)(r >> 16);
}

__global__ __launch_bounds__(256, 2) void sdpa_fa_kernel(
    const float* __restrict__ Q, const float* __restrict__ K,
    const float* __restrict__ V, const float* __restrict__ M,
    float* __restrict__ Out) {
  const int lane = threadIdx.x & 63;
  const int wave = threadIdx.x >> 6;
  const int q16 = lane & 15;   // column index in C/D layout
  const int h4  = lane >> 4;   // lane group 0..3

  const int head = blockIdx.x / (Sn / QB);   // b*H + h
  const int qblk = blockIdx.x % (Sn / QB);
  const int q0 = qblk * QB + wave * (QSUB * 16);

  const float* __restrict__ Qh = Q + (size_t)head * Sn * DKn;
  const float* __restrict__ Kh = K + (size_t)head * Sn * DKn;
  const float* __restrict__ Vh = V + (size_t)head * Sn * DVn;
  float* __restrict__ Oh = Out + (size_t)head * Sn * DVn;

  // ---- Q fragments (held in regs for whole kernel) ----
  // B-operand of S^T = K·Q^T: lane l elem j = Q[q0s + (l&15)][kc*32 + 8*h4 + j]
  Frag qf[QSUB][2];
#pragma unroll
  for (int s = 0; s < QSUB; ++s)
#pragma unroll
    for (int kc = 0; kc < 2; ++kc) {
      const float* p = Qh + (size_t)(q0 + s * 16 + q16) * DKn + kc * 32 + h4 * 8;
#pragma unroll
      for (int j = 0; j < 8; ++j) qf[s][kc].s[j] = f2bf(p[j]);
    }

  // ---- running state ----
  f32x4 acc[QSUB][4];                 // O^T accum: [sub][dtile], fp32
  float m_run[QSUB], l_run[QSUB];
#pragma unroll
  for (int s = 0; s < QSUB; ++s) {
    m_run[s] = -1e30f; l_run[s] = 0.f;
#pragma unroll
    for (int dt = 0; dt < 4; ++dt) acc[s][dt] = (f32x4){0.f, 0.f, 0.f, 0.f};
  }

  for (int kv0 = 0; kv0 < Sn; kv0 += 32) {
    // ---- K fragments: A-operand rows = kv. lane l elem j = K[kv0+16t+(l&15)][kc*32+8*h4+j]
    Frag kf[2][2];
#pragma unroll
    for (int t = 0; t < 2; ++t)
#pragma unroll
      for (int kc = 0; kc < 2; ++kc) {
        const float* p = Kh + (size_t)(kv0 + t * 16 + q16) * DKn + kc * 32 + h4 * 8;
#pragma unroll
        for (int j = 0; j < 8; ++j) kf[t][kc].s[j] = f2bf(p[j]);
      }

    // ---- V fragments (V^T A-operand): lane l elem j = V[kv0+8*h4+j][dt*16+(l&15)]
    Frag vf[4];
#pragma unroll
    for (int dt = 0; dt < 4; ++dt) {
#pragma unroll
      for (int j = 0; j < 8; ++j)
        vf[dt].s[j] = f2bf(Vh[(size_t)(kv0 + h4 * 8 + j) * DVn + dt * 16 + q16]);
    }

#pragma unroll
    for (int s = 0; s < QSUB; ++s) {
      // S^T tiles: [t] covers kv rows kv0+16t..+15; contract over DK=64 (2 chunks)
      f32x4 st[2];
#pragma unroll
      for (int t = 0; t < 2; ++t) {
        f32x4 z = (f32x4){0.f, 0.f, 0.f, 0.f};
        st[t] = __builtin_amdgcn_mfma_f32_16x16x32_bf16(kf[t][0].v, qf[s][0].v, z, 0, 0, 0);
        st[t] = __builtin_amdgcn_mfma_f32_16x16x32_bf16(kf[t][1].v, qf[s][1].v, st[t], 0, 0, 0);
      }

      // scale + additive mask; C/D layout: this lane holds S^T[kv=16t+4*h4+r][q=q0s+q16]
      const int q = q0 + s * 16 + q16;
      float sv[2][4];
      float mx = -1e30f;
#pragma unroll
      for (int t = 0; t < 2; ++t)
#pragma unroll
        for (int r = 0; r < 4; ++r) {
          sv[t][r] = st[t][r] * SCALE + M[(size_t)q * Sn + kv0 + t * 16 + h4 * 4 + r];
          mx = fmaxf(mx, sv[t][r]);
        }
      // block max across the 4 lane groups holding this q-column
      mx = fmaxf(mx, __shfl_xor(mx, 16, 64));
      mx = fmaxf(mx, __shfl_xor(mx, 32, 64));

      const float mn = fmaxf(m_run[s], mx);
      const float corr = __expf(m_run[s] - mn);
      m_run[s] = mn;

      float pv[2][4];
      float ps = 0.f;
#pragma unroll
      for (int t = 0; t < 2; ++t)
#pragma unroll
        for (int r = 0; r < 4; ++r) {
          pv[t][r] = __expf(sv[t][r] - mn);
          ps += pv[t][r];
        }
      ps += __shfl_xor(ps, 16, 64);
      ps += __shfl_xor(ps, 32, 64);
      l_run[s] = l_run[s] * corr + ps;

#pragma unroll
      for (int dt = 0; dt < 4; ++dt)
#pragma unroll
        for (int r = 0; r < 4; ++r) acc[s][dt][r] *= corr;

      // pack P to bf16 pairs: pk[t][0]=(r0,r1), pk[t][1]=(r2,r3)
      unsigned pk[2][2];
#pragma unroll
      for (int t = 0; t < 2; ++t) {
        pk[t][0] = (unsigned)f2bf(pv[t][0]) | ((unsigned)f2bf(pv[t][1]) << 16);
        pk[t][1] = (unsigned)f2bf(pv[t][2]) | ((unsigned)f2bf(pv[t][3]) << 16);
      }

      // Build P^T B-fragment: dest lane (h4,q16) elem j = P[q16][kv0+8*h4+j].
      // Source: reg r'=j&3 of tile t'=h4>>1 in lane 32*(h4&1) + 16*(j>=4) + q16.
      Frag pf;
      const int srcA = ((h4 & 1) << 5) + q16;
#pragma unroll
      for (int w = 0; w < 4; ++w) {
        const int src = srcA + ((w >= 2) ? 16 : 0);
        const unsigned v0 = (unsigned)__shfl((int)pk[0][w & 1], src, 64);
        const unsigned v1 = (unsigned)__shfl((int)pk[1][w & 1], src, 64);
        pf.u[w] = (h4 >> 1) ? v1 : v0;
      }

      // O^T += V^T · P^T
#pragma unroll
      for (int dt = 0; dt < 4; ++dt)
        acc[s][dt] = __builtin_amdgcn_mfma_f32_16x16x32_bf16(vf[dt].v, pf.v, acc[s][dt], 0, 0, 0);
    }
  }

  // ---- epilogue: normalize and write O (lane holds O^T[d=dt*16+4*h4+r][q=q16]) ----
#pragma unroll
  for (int s = 0; s < QSUB; ++s) {
    const float inv = 1.0f / l_run[s];
    const int q = q0 + s * 16 + q16;
#pragma unroll
    for (int dt = 0; dt < 4; ++dt)
#pragma unroll
      for (int r = 0; r < 4; ++r)
        Oh[(size_t)q * DVn + dt * 16 + h4 * 4 + r] = acc[s][dt][r] * inv;
  }
}

extern "C" void kernel_launch(void* const* d_in, const int* in_sizes, int n_in,
                              void* d_out, int out_size, void* d_ws, size_t ws_size,
                              hipStream_t stream) {
  const float* Q = (const float*)d_in[0];
  const float* K = (const float*)d_in[1];
  const float* V = (const float*)d_in[2];
  const float* M = (const float*)d_in[3];
  float* O = (float*)d_out;
  dim3 grid(Bn * Hn * (Sn / QB));
  sdpa_fa_kernel<<<grid, dim3(256), 0, stream>>>(Q, K, V, M, O);
}

// Round 2
// 205.281 us; speedup vs baseline: 2.8208x; 2.8208x over previous
//
#include <hip/hip_runtime.h>
#include <hip/hip_bf16.h>

// SDPA B=2,H=16,S=2048,DK=DV=64 fp32, additive mask (1,1,S,S).
// Flash attention: 4 waves/block, 128 q-rows/block, KV tile 64.
// K and V^T staged in LDS (bf16, XOR-swizzled 16B blocks), mask via coalesced
// float4 from global, P^T through per-wave LDS, T14 prefetch of next KV tile.

constexpr int Bn = 2, Hn = 16, Sn = 2048, DKn = 64;
constexpr int WAVES = 4, QSUB = 2;
constexpr int QB = WAVES * QSUB * 16;  // 128
constexpr int KVB = 64;
constexpr int NIT = Sn / KVB;          // 32
constexpr float SCALE = 0.125f;        // 1/sqrt(64)

typedef __attribute__((ext_vector_type(8))) short bf16x8;
typedef __attribute__((ext_vector_type(4))) short bf16x4;
typedef __attribute__((ext_vector_type(4))) float f32x4;

union Frag { bf16x8 v; unsigned short s[8]; };
union H4   { bf16x4 v; unsigned short s[4]; };

__device__ __forceinline__ unsigned short f2bf(float x) {
  union { float f; unsigned u; } c; c.f = x;
  unsigned r = c.u + 0x7FFFu + ((c.u >> 16) & 1u);
  return (unsigned short)(r >> 16);
}

__global__ __launch_bounds__(256, 2) void sdpa_fa2(
    const float* __restrict__ Q, const float* __restrict__ K,
    const float* __restrict__ V, const float* __restrict__ M,
    float* __restrict__ Out) {
  __shared__ unsigned short Kt[64 * 64];        // [kv][dk], 16B-block swizzled
  __shared__ unsigned short Vt[64 * 64];        // [d][kv], 16B-block swizzled
  __shared__ unsigned short Pt[WAVES * 16 * 64];// per-wave [q16][kv]

  const int tid = threadIdx.x;
  const int lane = tid & 63;
  const int wave = tid >> 6;
  const int q16 = lane & 15;
  const int h4 = lane >> 4;

  int bid = blockIdx.x;
  bid = (bid & 7) * ((int)gridDim.x >> 3) + (bid >> 3);  // XCD chunk swizzle (512%8==0)
  const int head = bid / (Sn / QB);
  const int qblk = bid % (Sn / QB);
  const int q0w = qblk * QB + wave * (QSUB * 16);

  const float* __restrict__ Qh = Q + (size_t)head * Sn * DKn;
  const float* __restrict__ Kh = K + (size_t)head * Sn * DKn;
  const float* __restrict__ Vh = V + (size_t)head * Sn * DKn;
  float* __restrict__ Oh = Out + (size_t)head * Sn * DKn;

  // ---- Q fragments (B-operand of S^T = K·Q^T), persistent ----
  Frag qf[QSUB][2];
#pragma unroll
  for (int s = 0; s < QSUB; ++s)
#pragma unroll
    for (int kc = 0; kc < 2; ++kc) {
      const float* p = Qh + (size_t)(q0w + s * 16 + q16) * DKn + kc * 32 + h4 * 8;
#pragma unroll
      for (int j = 0; j < 8; ++j) qf[s][kc].s[j] = f2bf(p[j]);
    }

  f32x4 acc[QSUB][4];
  float m_run[QSUB], l_run[QSUB];
#pragma unroll
  for (int s = 0; s < QSUB; ++s) {
    m_run[s] = -1e30f; l_run[s] = 0.f;
#pragma unroll
    for (int dt = 0; dt < 4; ++dt) acc[s][dt] = (f32x4){0.f, 0.f, 0.f, 0.f};
  }

  const int krow = tid >> 2, kcb = tid & 3;   // K staging: row, 16-float col group
  const int vk4 = tid >> 4, vcb = tid & 15;   // V staging: 4-row group, 4-float col group

  f32x4 kr[4], vr[4];
  {  // preload tile 0
    const float* kp = Kh + (size_t)krow * DKn + kcb * 16;
#pragma unroll
    for (int u = 0; u < 4; ++u) kr[u] = *(const f32x4*)(kp + 4 * u);
    const float* vp = Vh + (size_t)(4 * vk4) * DKn + vcb * 4;
#pragma unroll
    for (int r = 0; r < 4; ++r) vr[r] = *(const f32x4*)(vp + (size_t)r * DKn);
  }

  for (int it = 0; it < NIT; ++it) {
    const int kv0 = it * KVB;
    __syncthreads();  // prev-iter LDS reads complete before overwrite

    // ---- staged regs -> LDS (convert to bf16) ----
#pragma unroll
    for (int b = 0; b < 2; ++b) {  // K row krow, dk = 16*kcb + 8b .. +7
      Frag fr;
#pragma unroll
      for (int j = 0; j < 8; ++j) fr.s[j] = f2bf(kr[2 * b + (j >> 2)][j & 3]);
      const int c16p = (2 * kcb + b) ^ (krow & 7);
      *(bf16x8*)&Kt[krow * 64 + c16p * 8] = fr.v;
    }
#pragma unroll
    for (int j = 0; j < 4; ++j) {  // V^T row d = 4*vcb+j, kv = 4*vk4 .. +3
      H4 ph;
#pragma unroll
      for (int r = 0; r < 4; ++r) ph.s[r] = f2bf(vr[r][j]);
      const int d = 4 * vcb + j;
      const int c16p = (vk4 >> 1) ^ (d & 7);
      *(bf16x4*)&Vt[d * 64 + c16p * 8 + (vk4 & 1) * 4] = ph.v;
    }
    __syncthreads();

    // ---- T14: issue next tile's global loads now, consume next iter ----
    if (it + 1 < NIT) {
      const float* kp = Kh + (size_t)(kv0 + KVB + krow) * DKn + kcb * 16;
#pragma unroll
      for (int u = 0; u < 4; ++u) kr[u] = *(const f32x4*)(kp + 4 * u);
      const float* vp = Vh + (size_t)(kv0 + KVB + 4 * vk4) * DKn + vcb * 4;
#pragma unroll
      for (int r = 0; r < 4; ++r) vr[r] = *(const f32x4*)(vp + (size_t)r * DKn);
    }

    // ---- fragment reads from LDS ----
    Frag kf[4][2], vf[4][2];
#pragma unroll
    for (int t = 0; t < 4; ++t)
#pragma unroll
      for (int kc = 0; kc < 2; ++kc)
        kf[t][kc].v = *(const bf16x8*)&Kt[(16 * t + q16) * 64 + ((4 * kc + h4) ^ (q16 & 7)) * 8];
#pragma unroll
    for (int dt = 0; dt < 4; ++dt)
#pragma unroll
      for (int c = 0; c < 2; ++c)
        vf[dt][c].v = *(const bf16x8*)&Vt[(dt * 16 + q16) * 64 + ((4 * c + h4) ^ (q16 & 7)) * 8];

#pragma unroll
    for (int s = 0; s < QSUB; ++s) {
      const int q = q0w + s * 16 + q16;
      const float* mrow = M + (size_t)q * Sn + kv0;
      f32x4 mk[4];
#pragma unroll
      for (int t = 0; t < 4; ++t) mk[t] = *(const f32x4*)(mrow + 16 * t + 4 * h4);

      f32x4 st[4];
      __builtin_amdgcn_s_setprio(1);
#pragma unroll
      for (int t = 0; t < 4; ++t) {
        f32x4 z = (f32x4){0.f, 0.f, 0.f, 0.f};
        z = __builtin_amdgcn_mfma_f32_16x16x32_bf16(kf[t][0].v, qf[s][0].v, z, 0, 0, 0);
        st[t] = __builtin_amdgcn_mfma_f32_16x16x32_bf16(kf[t][1].v, qf[s][1].v, z, 0, 0, 0);
      }
      __builtin_amdgcn_s_setprio(0);

      float sv[4][4];
      float mx = -1e30f;
#pragma unroll
      for (int t = 0; t < 4; ++t)
#pragma unroll
        for (int r = 0; r < 4; ++r) {
          sv[t][r] = st[t][r] * SCALE + mk[t][r];
          mx = fmaxf(mx, sv[t][r]);
        }
      mx = fmaxf(mx, __shfl_xor(mx, 16, 64));
      mx = fmaxf(mx, __shfl_xor(mx, 32, 64));

      const float mn = fmaxf(m_run[s], mx);
      const float corr = __expf(m_run[s] - mn);
      m_run[s] = mn;

      float ps = 0.f;
#pragma unroll
      for (int t = 0; t < 4; ++t) {
        H4 ph;
#pragma unroll
        for (int r = 0; r < 4; ++r) {
          const float p = __expf(sv[t][r] - mn);
          ps += p;
          ph.s[r] = f2bf(p);
        }
        // P^T write: row q16, kv = 16t+4h4 .. +3 (b64)
        *(bf16x4*)&Pt[wave * 1024 + q16 * 64 + ((2 * t + (h4 >> 1)) ^ (q16 & 7)) * 8 + (h4 & 1) * 4] = ph.v;
      }
      ps += __shfl_xor(ps, 16, 64);
      ps += __shfl_xor(ps, 32, 64);
      l_run[s] = l_run[s] * corr + ps;

#pragma unroll
      for (int dt = 0; dt < 4; ++dt)
#pragma unroll
        for (int r = 0; r < 4; ++r) acc[s][dt][r] *= corr;

      Frag pf[2];
#pragma unroll
      for (int c = 0; c < 2; ++c)
        pf[c].v = *(const bf16x8*)&Pt[wave * 1024 + q16 * 64 + ((4 * c + h4) ^ (q16 & 7)) * 8];

      __builtin_amdgcn_s_setprio(1);
#pragma unroll
      for (int dt = 0; dt < 4; ++dt)
#pragma unroll
        for (int c = 0; c < 2; ++c)
          acc[s][dt] = __builtin_amdgcn_mfma_f32_16x16x32_bf16(vf[dt][c].v, pf[c].v, acc[s][dt], 0, 0, 0);
      __builtin_amdgcn_s_setprio(0);
    }
  }

  // ---- epilogue: O[q][d], lane holds d = dt*16 + 4*h4 + r (r contiguous) ----
#pragma unroll
  for (int s = 0; s < QSUB; ++s) {
    const float inv = 1.0f / l_run[s];
    const int q = q0w + s * 16 + q16;
#pragma unroll
    for (int dt = 0; dt < 4; ++dt) {
      f32x4 o = acc[s][dt];
      o[0] *= inv; o[1] *= inv; o[2] *= inv; o[3] *= inv;
      *(f32x4*)&Oh[(size_t)q * DKn + dt * 16 + 4 * h4] = o;
    }
  }
}

extern "C" void kernel_launch(void* const* d_in, const int* in_sizes, int n_in,
                              void* d_out, int out_size, void* d_ws, size_t ws_size,
                              hipStream_t stream) {
  const float* Q = (const float*)d_in[0];
  const float* K = (const float*)d_in[1];
  const float* V = (const float*)d_in[2];
  const float* M = (const float*)d_in[3];
  float* O = (float*)d_out;
  dim3 grid(Bn * Hn * (Sn / QB));
  sdpa_fa2<<<grid, dim3(256), 0, stream>>>(Q, K, V, M, O);
}

// Round 3
// 190.744 us; speedup vs baseline: 3.0358x; 1.0762x over previous
//
#include <hip/hip_runtime.h>

// SDPA B=2,H=16,S=2048,DK=DV=64 fp32, additive mask (1,1,S,S).
// 32x32x16-MFMA flash attention, in-register softmax (swapped QK^T),
// P->PV fragments built in-register via partner-lane exchange (no P LDS).
// 4 waves/block, 32 q-rows/wave (QB=128), KV tile 64 (2 sub-tiles of 32),
// K/V^T double-buffered bf16 LDS, T14 issue-early/write-late staging.

constexpr int Bn = 2, Hn = 16, Sn = 2048, Dn = 64;
constexpr int QB = 128;
constexpr int KVB = 64;
constexpr int NIT = Sn / KVB;   // 32
constexpr float SCALE = 0.125f; // 1/sqrt(64), exact power of 2
constexpr float DEFER_THR = 8.0f;

typedef __attribute__((ext_vector_type(8))) short bf16x8;
typedef __attribute__((ext_vector_type(4))) float f32x4;
typedef __attribute__((ext_vector_type(16))) float f32x16;

union FragU { bf16x8 v; unsigned u[4]; };

__device__ __forceinline__ unsigned cvt_pk(float lo, float hi) {
  unsigned r;
  asm("v_cvt_pk_bf16_f32 %0, %1, %2" : "=v"(r) : "v"(lo), "v"(hi));
  return r;
}

__global__ __launch_bounds__(256, 2) void sdpa_fa3(
    const float* __restrict__ Q, const float* __restrict__ K,
    const float* __restrict__ V, const float* __restrict__ M,
    float* __restrict__ Out) {
  __shared__ unsigned short Kt[2][64 * 64];  // [buf][kv][dk], 16B-block swizzled
  __shared__ unsigned short Vt[2][64 * 64];  // [buf][d][kv], 16B-block swizzled

  const int tid = threadIdx.x;
  const int lane = tid & 63;
  const int wave = tid >> 6;
  const int l31 = lane & 31;
  const int hi = lane >> 5;
  const int l7 = lane & 7;

  int bid = blockIdx.x;
  bid = (bid & 7) * ((int)gridDim.x >> 3) + (bid >> 3);  // XCD chunk swizzle
  const int head = bid >> 4;   // / (Sn/QB)=16
  const int qblk = bid & 15;
  const int qrow = qblk * QB + wave * 32 + l31;

  const float* __restrict__ Qh = Q + (size_t)head * Sn * Dn;
  const float* __restrict__ Kh = K + (size_t)head * Sn * Dn;
  const float* __restrict__ Vh = V + (size_t)head * Sn * Dn;
  float* __restrict__ Oh = Out + (size_t)head * Sn * Dn;
  const float* __restrict__ Mrow = M + (size_t)qrow * Sn;

  // ---- Q fragments (B-operand), pre-scaled by 1/sqrt(dk) ----
  FragU qf[4];
#pragma unroll
  for (int kc = 0; kc < 4; ++kc) {
    const float* p = Qh + (size_t)qrow * Dn + kc * 16 + hi * 8;
    f32x4 a = *(const f32x4*)p;
    f32x4 b = *(const f32x4*)(p + 4);
    qf[kc].u[0] = cvt_pk(a[0] * SCALE, a[1] * SCALE);
    qf[kc].u[1] = cvt_pk(a[2] * SCALE, a[3] * SCALE);
    qf[kc].u[2] = cvt_pk(b[0] * SCALE, b[1] * SCALE);
    qf[kc].u[3] = cvt_pk(b[2] * SCALE, b[3] * SCALE);
  }

  f32x16 acc0, acc1;
#pragma unroll
  for (int i = 0; i < 16; ++i) { acc0[i] = 0.f; acc1[i] = 0.f; }
  float m_run = -1e30f, l_run = 0.f;

  // staging thread roles (256 threads stage 64x64 K and V each)
  const int krow = tid >> 2, kcb = tid & 3;   // K: row, 16-float col group
  const int vk4 = tid >> 4, vcb = tid & 15;   // V: 4-row group, 4-float col group

  f32x4 kr[4], vr[4];
  // ---- prologue: load + stage tile 0 into buf 0 ----
  {
    const float* kp = Kh + (size_t)krow * Dn + kcb * 16;
#pragma unroll
    for (int u = 0; u < 4; ++u) kr[u] = *(const f32x4*)(kp + 4 * u);
    const float* vp = Vh + (size_t)(4 * vk4) * Dn + vcb * 4;
#pragma unroll
    for (int r = 0; r < 4; ++r) vr[r] = *(const f32x4*)(vp + (size_t)r * Dn);
#pragma unroll
    for (int b = 0; b < 2; ++b) {
      FragU f;
      f.u[0] = cvt_pk(kr[2 * b][0], kr[2 * b][1]);
      f.u[1] = cvt_pk(kr[2 * b][2], kr[2 * b][3]);
      f.u[2] = cvt_pk(kr[2 * b + 1][0], kr[2 * b + 1][1]);
      f.u[3] = cvt_pk(kr[2 * b + 1][2], kr[2 * b + 1][3]);
      const int pos = (2 * kcb + b) ^ (krow & 7);
      *(bf16x8*)&Kt[0][krow * 64 + pos * 8] = f.v;
    }
#pragma unroll
    for (int j = 0; j < 4; ++j) {
      const int d = 4 * vcb + j;
      unsigned w0 = cvt_pk(vr[0][j], vr[1][j]);
      unsigned w1 = cvt_pk(vr[2][j], vr[3][j]);
      const int pos = (vk4 >> 1) ^ (d & 7);
      unsigned* dst = (unsigned*)&Vt[0][d * 64 + pos * 8 + (vk4 & 1) * 4];
      dst[0] = w0; dst[1] = w1;
    }
  }
  __syncthreads();

  for (int it = 0; it < NIT; ++it) {
    const int kv0 = it * KVB;
    const int cur = it & 1;
    const unsigned short* Kb = Kt[cur];
    const unsigned short* Vb = Vt[cur];

    // ---- T14 issue-early: next tile's global loads ----
    if (it + 1 < NIT) {
      const float* kp = Kh + (size_t)(kv0 + KVB + krow) * Dn + kcb * 16;
#pragma unroll
      for (int u = 0; u < 4; ++u) kr[u] = *(const f32x4*)(kp + 4 * u);
      const float* vp = Vh + (size_t)(kv0 + KVB + 4 * vk4) * Dn + vcb * 4;
#pragma unroll
      for (int r = 0; r < 4; ++r) vr[r] = *(const f32x4*)(vp + (size_t)r * Dn);
    }

#pragma unroll
    for (int t = 0; t < 2; ++t) {
      // mask quads: lane holds kv = kv0 + 32t + 8m + 4hi + e
      f32x4 mk[4];
#pragma unroll
      for (int m = 0; m < 4; ++m)
        mk[m] = *(const f32x4*)(Mrow + kv0 + 32 * t + 8 * m + 4 * hi);

      // QK^T: S^T tile [kv 32][q 32], contract DK=64 in 4 chunks
      f32x16 st;
#pragma unroll
      for (int i = 0; i < 16; ++i) st[i] = 0.f;
      __builtin_amdgcn_s_setprio(1);
#pragma unroll
      for (int kc = 0; kc < 4; ++kc) {
        FragU kf;
        kf.v = *(const bf16x8*)&Kb[(32 * t + l31) * 64 + (((2 * kc + hi) ^ l7) * 8)];
        st = __builtin_amdgcn_mfma_f32_32x32x16_bf16(kf.v, qf[kc].v, st, 0, 0, 0);
      }
      __builtin_amdgcn_s_setprio(0);

      // add mask; per-lane row max over 16 values
      float p[16];
#pragma unroll
      for (int m = 0; m < 4; ++m)
#pragma unroll
        for (int e = 0; e < 4; ++e) p[4 * m + e] = st[4 * m + e] + mk[m][e];

      float t8[8];
#pragma unroll
      for (int i = 0; i < 8; ++i) t8[i] = fmaxf(p[2 * i], p[2 * i + 1]);
      float t4a = fmaxf(t8[0], t8[1]), t4b = fmaxf(t8[2], t8[3]);
      float t4c = fmaxf(t8[4], t8[5]), t4d = fmaxf(t8[6], t8[7]);
      float mx = fmaxf(fmaxf(t4a, t4b), fmaxf(t4c, t4d));
      mx = fmaxf(mx, __shfl_xor(mx, 32, 64));  // combine with partner half-row

      // T13 defer-max
      if (!__all(mx <= m_run + DEFER_THR)) {
        const float mn = fmaxf(m_run, mx);
        const float corr = __expf(m_run - mn);
        m_run = mn;
        l_run *= corr;
#pragma unroll
        for (int i = 0; i < 16; ++i) { acc0[i] *= corr; acc1[i] *= corr; }
      }

      float ps = 0.f;
#pragma unroll
      for (int i = 0; i < 16; ++i) {
        p[i] = __expf(p[i] - m_run);
        ps += p[i];
      }
      ps += __shfl_xor(ps, 32, 64);
      l_run += ps;

      // pack P quads: W[m][s] = bf16(p[4m+2s]), bf16(p[4m+2s+1])
      unsigned W[4][2];
#pragma unroll
      for (int m = 0; m < 4; ++m)
#pragma unroll
        for (int s = 0; s < 2; ++s)
          W[m][s] = cvt_pk(p[4 * m + 2 * s], p[4 * m + 2 * s + 1]);

      // build P^T B-fragments via partner-lane exchange
      FragU pf[2];
#pragma unroll
      for (int cc = 0; cc < 2; ++cc)
#pragma unroll
        for (int s = 0; s < 2; ++s) {
          const unsigned a = W[2 * cc][s];
          const unsigned b = W[2 * cc + 1][s];
          const unsigned pa = (unsigned)__shfl_xor((int)a, 32, 64);
          const unsigned pb = (unsigned)__shfl_xor((int)b, 32, 64);
          pf[cc].u[s] = hi ? pb : a;
          pf[cc].u[2 + s] = hi ? b : pa;
        }

      // PV: O^T += V^T . P^T
      __builtin_amdgcn_s_setprio(1);
#pragma unroll
      for (int cc = 0; cc < 2; ++cc) {
        const int c = 2 * t + cc;
        FragU vf0, vf1;
        vf0.v = *(const bf16x8*)&Vb[(l31) * 64 + (((2 * c + hi) ^ l7) * 8)];
        vf1.v = *(const bf16x8*)&Vb[(32 + l31) * 64 + (((2 * c + hi) ^ l7) * 8)];
        acc0 = __builtin_amdgcn_mfma_f32_32x32x16_bf16(vf0.v, pf[cc].v, acc0, 0, 0, 0);
        acc1 = __builtin_amdgcn_mfma_f32_32x32x16_bf16(vf1.v, pf[cc].v, acc1, 0, 0, 0);
      }
      __builtin_amdgcn_s_setprio(0);
    }

    // ---- write-late: stage tile it+1 into buf cur^1 ----
    if (it + 1 < NIT) {
#pragma unroll
      for (int b = 0; b < 2; ++b) {
        FragU f;
        f.u[0] = cvt_pk(kr[2 * b][0], kr[2 * b][1]);
        f.u[1] = cvt_pk(kr[2 * b][2], kr[2 * b][3]);
        f.u[2] = cvt_pk(kr[2 * b + 1][0], kr[2 * b + 1][1]);
        f.u[3] = cvt_pk(kr[2 * b + 1][2], kr[2 * b + 1][3]);
        const int pos = (2 * kcb + b) ^ (krow & 7);
        *(bf16x8*)&Kt[cur ^ 1][krow * 64 + pos * 8] = f.v;
      }
#pragma unroll
      for (int j = 0; j < 4; ++j) {
        const int d = 4 * vcb + j;
        unsigned w0 = cvt_pk(vr[0][j], vr[1][j]);
        unsigned w1 = cvt_pk(vr[2][j], vr[3][j]);
        const int pos = (vk4 >> 1) ^ (d & 7);
        unsigned* dst = (unsigned*)&Vt[cur ^ 1][d * 64 + pos * 8 + (vk4 & 1) * 4];
        dst[0] = w0; dst[1] = w1;
      }
    }
    __syncthreads();
  }

  // ---- epilogue: O[q][d], lane q = l31; d = 32*dt + 8m + 4hi + e ----
  const float inv = 1.0f / l_run;
#pragma unroll
  for (int m = 0; m < 4; ++m) {
    f32x4 o0, o1;
#pragma unroll
    for (int e = 0; e < 4; ++e) { o0[e] = acc0[4 * m + e] * inv; o1[e] = acc1[4 * m + e] * inv; }
    *(f32x4*)&Oh[(size_t)qrow * Dn + 8 * m + 4 * hi] = o0;
    *(f32x4*)&Oh[(size_t)qrow * Dn + 32 + 8 * m + 4 * hi] = o1;
  }
}

extern "C" void kernel_launch(void* const* d_in, const int* in_sizes, int n_in,
                              void* d_out, int out_size, void* d_ws, size_t ws_size,
                              hipStream_t stream) {
  const float* Q = (const float*)d_in[0];
  const float* K = (const float*)d_in[1];
  const float* V = (const float*)d_in[2];
  const float* M = (const float*)d_in[3];
  float* O = (float*)d_out;
  dim3 grid(Bn * Hn * (Sn / QB));  // 512
  sdpa_fa3<<<grid, dim3(256), 0, stream>>>(Q, K, V, M, O);
}

// Round 4
// 186.044 us; speedup vs baseline: 3.1125x; 1.0253x over previous
//
#include <hip/hip_runtime.h>

// SDPA B=2,H=16,S=2048,DK=DV=64 fp32, additive mask (1,1,S,S).
// 32x32x16-MFMA flash attention, in-register softmax (swapped QK^T, exp2 domain),
// in-block split-K x2: waves 0-3 do kv [0,1024), waves 4-7 do [1024,2048),
// merged via LDS. KVB=32, K/V^T/mask all staged coalesced in double-buffered
// bf16 LDS. All LDS access patterns at the ds_read_b128 bank floor.

constexpr int Bn = 2, Hn = 16, Sn = 2048, Dn = 64;
constexpr int QB = 128;         // q rows per block
constexpr int KVB = 32;         // kv per iteration per half
constexpr int HALFKV = 1024;    // kv range per half
constexpr int NIT = HALFKV / KVB;  // 32
constexpr float LOG2E = 1.44269504088896f;
constexpr float QSCALE = 0.125f * LOG2E;   // 1/sqrt(64) * log2(e)
constexpr float DEFER_THR = 8.0f;          // in log2 units

typedef __attribute__((ext_vector_type(8))) short bf16x8;
typedef __attribute__((ext_vector_type(4))) float f32x4;
typedef __attribute__((ext_vector_type(16))) float f32x16;

union FragU { bf16x8 v; unsigned u[4]; unsigned short s[8]; };
union B64U { unsigned long long q; unsigned short s[4]; };

__device__ __forceinline__ unsigned cvt_pk(float lo, float hi) {
  unsigned r;
  asm("v_cvt_pk_bf16_f32 %0, %1, %2" : "=v"(r) : "v"(lo), "v"(hi));
  return r;
}
__device__ __forceinline__ float exp2_fast(float x) {
  float r;
  asm("v_exp_f32 %0, %1" : "=v"(r) : "v"(x));
  return r;
}
__device__ __forceinline__ float bf2f(unsigned short b) {
  union { unsigned u; float f; } c;
  c.u = ((unsigned)b) << 16;
  return c.f;
}

__global__ __launch_bounds__(512, 4) void sdpa_fa4(
    const float* __restrict__ Q, const float* __restrict__ K,
    const float* __restrict__ V, const float* __restrict__ M,
    float* __restrict__ Out) {
  // Per half (16384 shorts = 32KB):
  //   Kt [2][32 kv][64 dk]  swz pos = blk ^ (kv&7)       (8KB)
  //   Vt [2][64 d][32 kv]   swz pos = blk ^ ((d>>2)&3)   (8KB)
  //   Mt [2][128 q][32 kv]  swz pos = blk ^ (q&3)        (16KB)
  __shared__ __align__(16) unsigned short lds[32768];  // 64KB

  const int tid = threadIdx.x;
  const int lane = tid & 63;
  const int wave = tid >> 6;    // 0..7
  const int wq = wave & 3;      // q-tile index
  const int half = tid >> 8;    // kv half
  const int htid = tid & 255;
  const int l31 = lane & 31;
  const int hi = lane >> 5;

  int bid = blockIdx.x;
  bid = (bid & 7) * ((int)gridDim.x >> 3) + (bid >> 3);  // XCD chunk swizzle
  const int head = bid >> 4;    // blocks/head = 2048/128 = 16
  const int qblk = bid & 15;
  const int qrow = qblk * QB + wq * 32 + l31;
  const int kvh = half * HALFKV;

  const float* __restrict__ Qh = Q + (size_t)head * Sn * Dn;
  const float* __restrict__ Kh = K + (size_t)head * Sn * Dn;
  const float* __restrict__ Vh = V + (size_t)head * Sn * Dn;
  float* __restrict__ Oh = Out + (size_t)head * Sn * Dn;

  unsigned short* Kt = lds + half * 16384;
  unsigned short* Vt = lds + half * 16384 + 4096;
  unsigned short* Mt = lds + half * 16384 + 8192;

  // ---- Q fragments (B-operand of S^T=K.Q^T), pre-scaled by QSCALE ----
  FragU qf[4];
#pragma unroll
  for (int kc = 0; kc < 4; ++kc) {
    const float* p = Qh + (size_t)qrow * Dn + kc * 16 + hi * 8;
    f32x4 a = *(const f32x4*)p;
    f32x4 b = *(const f32x4*)(p + 4);
    qf[kc].u[0] = cvt_pk(a[0] * QSCALE, a[1] * QSCALE);
    qf[kc].u[1] = cvt_pk(a[2] * QSCALE, a[3] * QSCALE);
    qf[kc].u[2] = cvt_pk(b[0] * QSCALE, b[1] * QSCALE);
    qf[kc].u[3] = cvt_pk(b[2] * QSCALE, b[3] * QSCALE);
  }

  f32x16 acc0, acc1;
#pragma unroll
  for (int i = 0; i < 16; ++i) { acc0[i] = 0.f; acc1[i] = 0.f; }
  float m_run = -1e30f, l_run = 0.f;

  // staging roles (256 threads per half)
  const int krow = htid >> 3, kcb = htid & 7;  // K: kv row, 8-dk block
  const int vd = htid & 63, vkb = htid >> 6;   // V: d col, 8-kv block
  const int mq = htid >> 1, mh = htid & 1;     // M: q row, 16-kv half-row

  f32x4 kr0, kr1;  // K stage regs (8 f32)
  float vrg[8];    // V stage regs
  f32x4 mr[4];     // M stage regs (16 f32)

  // ---- prologue: load + stage tile 0 into buf 0 ----
  {
    const float* kp = Kh + (size_t)(kvh + krow) * Dn + kcb * 8;
    kr0 = *(const f32x4*)kp;
    kr1 = *(const f32x4*)(kp + 4);
    const float* vp = Vh + (size_t)(kvh + vkb * 8) * Dn + vd;
#pragma unroll
    for (int r = 0; r < 8; ++r) vrg[r] = vp[(size_t)r * Dn];
    const float* mp = M + (size_t)(qblk * QB + mq) * Sn + kvh + mh * 16;
#pragma unroll
    for (int u = 0; u < 4; ++u) mr[u] = *(const f32x4*)(mp + 4 * u);

    FragU f;
    f.u[0] = cvt_pk(kr0[0], kr0[1]); f.u[1] = cvt_pk(kr0[2], kr0[3]);
    f.u[2] = cvt_pk(kr1[0], kr1[1]); f.u[3] = cvt_pk(kr1[2], kr1[3]);
    *(bf16x8*)&Kt[krow * 64 + ((kcb ^ (krow & 7)) * 8)] = f.v;
    FragU g;
    g.u[0] = cvt_pk(vrg[0], vrg[1]); g.u[1] = cvt_pk(vrg[2], vrg[3]);
    g.u[2] = cvt_pk(vrg[4], vrg[5]); g.u[3] = cvt_pk(vrg[6], vrg[7]);
    *(bf16x8*)&Vt[vd * 32 + ((vkb ^ ((vd >> 2) & 3)) * 8)] = g.v;
    FragU h0, h1;
    h0.u[0] = cvt_pk(mr[0][0] * LOG2E, mr[0][1] * LOG2E);
    h0.u[1] = cvt_pk(mr[0][2] * LOG2E, mr[0][3] * LOG2E);
    h0.u[2] = cvt_pk(mr[1][0] * LOG2E, mr[1][1] * LOG2E);
    h0.u[3] = cvt_pk(mr[1][2] * LOG2E, mr[1][3] * LOG2E);
    h1.u[0] = cvt_pk(mr[2][0] * LOG2E, mr[2][1] * LOG2E);
    h1.u[1] = cvt_pk(mr[2][2] * LOG2E, mr[2][3] * LOG2E);
    h1.u[2] = cvt_pk(mr[3][0] * LOG2E, mr[3][1] * LOG2E);
    h1.u[3] = cvt_pk(mr[3][2] * LOG2E, mr[3][3] * LOG2E);
    *(bf16x8*)&Mt[mq * 32 + (((mh * 2 + 0) ^ (mq & 3)) * 8)] = h0.v;
    *(bf16x8*)&Mt[mq * 32 + (((mh * 2 + 1) ^ (mq & 3)) * 8)] = h1.v;
  }
  __syncthreads();

  for (int it = 0; it < NIT; ++it) {
    const int cur = it & 1;
    const unsigned short* Kb = Kt + cur * 2048;
    const unsigned short* Vb = Vt + cur * 2048;
    const unsigned short* Mb = Mt + cur * 4096;

    // ---- T14 issue-early: next tile's global loads ----
    if (it + 1 < NIT) {
      const int kv1 = kvh + (it + 1) * KVB;
      const float* kp = Kh + (size_t)(kv1 + krow) * Dn + kcb * 8;
      kr0 = *(const f32x4*)kp;
      kr1 = *(const f32x4*)(kp + 4);
      const float* vp = Vh + (size_t)(kv1 + vkb * 8) * Dn + vd;
#pragma unroll
      for (int r = 0; r < 8; ++r) vrg[r] = vp[(size_t)r * Dn];
      const float* mp = M + (size_t)(qblk * QB + mq) * Sn + kv1 + mh * 16;
#pragma unroll
      for (int u = 0; u < 4; ++u) mr[u] = *(const f32x4*)(mp + 4 * u);
    }

    // ---- QK^T: S^T [kv 32][q 32], contract DK=64 ----
    f32x16 st;
#pragma unroll
    for (int i = 0; i < 16; ++i) st[i] = 0.f;
    __builtin_amdgcn_s_setprio(1);
#pragma unroll
    for (int kc = 0; kc < 4; ++kc) {
      FragU kf;
      kf.v = *(const bf16x8*)&Kb[l31 * 64 + (((2 * kc + hi) ^ (l31 & 7)) * 8)];
      st = __builtin_amdgcn_mfma_f32_32x32x16_bf16(kf.v, qf[kc].v, st, 0, 0, 0);
    }
    __builtin_amdgcn_s_setprio(0);

    // ---- mask add (bf16 from LDS, already log2e-scaled) ----
    float p[16];
#pragma unroll
    for (int m = 0; m < 4; ++m) {
      B64U mb;
      mb.q = *(const unsigned long long*)
          &Mb[(wq * 32 + l31) * 32 + ((m ^ (l31 & 3)) * 8) + hi * 4];
#pragma unroll
      for (int e = 0; e < 4; ++e) p[4 * m + e] = st[4 * m + e] + bf2f(mb.s[e]);
    }

    // ---- row max (16-value tree + partner) ----
    float t8[8];
#pragma unroll
    for (int i = 0; i < 8; ++i) t8[i] = fmaxf(p[2 * i], p[2 * i + 1]);
    float t4a = fmaxf(t8[0], t8[1]), t4b = fmaxf(t8[2], t8[3]);
    float t4c = fmaxf(t8[4], t8[5]), t4d = fmaxf(t8[6], t8[7]);
    float mx = fmaxf(fmaxf(t4a, t4b), fmaxf(t4c, t4d));
    mx = fmaxf(mx, __shfl_xor(mx, 32, 64));

    // T13 defer-max
    if (!__all(mx <= m_run + DEFER_THR)) {
      const float mn = fmaxf(m_run, mx);
      const float corr = exp2_fast(m_run - mn);
      m_run = mn;
      l_run *= corr;
#pragma unroll
      for (int i = 0; i < 16; ++i) { acc0[i] *= corr; acc1[i] *= corr; }
    }

    float ps = 0.f;
#pragma unroll
    for (int i = 0; i < 16; ++i) {
      p[i] = exp2_fast(p[i] - m_run);
      ps += p[i];
    }
    ps += __shfl_xor(ps, 32, 64);
    l_run += ps;

    // ---- pack P, build P^T B-fragments via partner exchange ----
    unsigned W[4][2];
#pragma unroll
    for (int m = 0; m < 4; ++m)
#pragma unroll
      for (int s = 0; s < 2; ++s)
        W[m][s] = cvt_pk(p[4 * m + 2 * s], p[4 * m + 2 * s + 1]);

    FragU pf[2];
#pragma unroll
    for (int cc = 0; cc < 2; ++cc)
#pragma unroll
      for (int s = 0; s < 2; ++s) {
        const unsigned a = W[2 * cc][s];
        const unsigned b = W[2 * cc + 1][s];
        const unsigned pa = (unsigned)__shfl_xor((int)a, 32, 64);
        const unsigned pb = (unsigned)__shfl_xor((int)b, 32, 64);
        pf[cc].u[s] = hi ? pb : a;
        pf[cc].u[2 + s] = hi ? b : pa;
      }

    // ---- PV: O^T += V^T . P^T ----
    __builtin_amdgcn_s_setprio(1);
#pragma unroll
    for (int c = 0; c < 2; ++c) {
      FragU vf0, vf1;
      vf0.v = *(const bf16x8*)&Vb[l31 * 32 + (((2 * c + hi) ^ ((l31 >> 2) & 3)) * 8)];
      vf1.v = *(const bf16x8*)&Vb[(32 + l31) * 32 + (((2 * c + hi) ^ ((l31 >> 2) & 3)) * 8)];
      acc0 = __builtin_amdgcn_mfma_f32_32x32x16_bf16(vf0.v, pf[c].v, acc0, 0, 0, 0);
      acc1 = __builtin_amdgcn_mfma_f32_32x32x16_bf16(vf1.v, pf[c].v, acc1, 0, 0, 0);
    }
    __builtin_amdgcn_s_setprio(0);

    // ---- write-late: stage tile it+1 into buf cur^1 ----
    if (it + 1 < NIT) {
      unsigned short* Kw = Kt + (cur ^ 1) * 2048;
      unsigned short* Vw = Vt + (cur ^ 1) * 2048;
      unsigned short* Mw = Mt + (cur ^ 1) * 4096;
      FragU f;
      f.u[0] = cvt_pk(kr0[0], kr0[1]); f.u[1] = cvt_pk(kr0[2], kr0[3]);
      f.u[2] = cvt_pk(kr1[0], kr1[1]); f.u[3] = cvt_pk(kr1[2], kr1[3]);
      *(bf16x8*)&Kw[krow * 64 + ((kcb ^ (krow & 7)) * 8)] = f.v;
      FragU g;
      g.u[0] = cvt_pk(vrg[0], vrg[1]); g.u[1] = cvt_pk(vrg[2], vrg[3]);
      g.u[2] = cvt_pk(vrg[4], vrg[5]); g.u[3] = cvt_pk(vrg[6], vrg[7]);
      *(bf16x8*)&Vw[vd * 32 + ((vkb ^ ((vd >> 2) & 3)) * 8)] = g.v;
      FragU h0, h1;
      h0.u[0] = cvt_pk(mr[0][0] * LOG2E, mr[0][1] * LOG2E);
      h0.u[1] = cvt_pk(mr[0][2] * LOG2E, mr[0][3] * LOG2E);
      h0.u[2] = cvt_pk(mr[1][0] * LOG2E, mr[1][1] * LOG2E);
      h0.u[3] = cvt_pk(mr[1][2] * LOG2E, mr[1][3] * LOG2E);
      h1.u[0] = cvt_pk(mr[2][0] * LOG2E, mr[2][1] * LOG2E);
      h1.u[1] = cvt_pk(mr[2][2] * LOG2E, mr[2][3] * LOG2E);
      h1.u[2] = cvt_pk(mr[3][0] * LOG2E, mr[3][1] * LOG2E);
      h1.u[3] = cvt_pk(mr[3][2] * LOG2E, mr[3][3] * LOG2E);
      *(bf16x8*)&Mw[mq * 32 + (((mh * 2 + 0) ^ (mq & 3)) * 8)] = h0.v;
      *(bf16x8*)&Mw[mq * 32 + (((mh * 2 + 1) ^ (mq & 3)) * 8)] = h1.v;
    }
    __syncthreads();
  }

  // ---- split-K merge through LDS ----
  float* Om = (float*)lds;                 // [4 wq][32 q][68] f32 (stride 68: 16B-aligned)
  float* Mm = (float*)lds + 4 * 32 * 68;   // [128]
  float* Lm = Mm + 128;                    // [128]

  if (half) {
    float* base = Om + (wq * 32 + l31) * 68;
#pragma unroll
    for (int m = 0; m < 4; ++m) {
      f32x4 a, b;
#pragma unroll
      for (int e = 0; e < 4; ++e) { a[e] = acc0[4 * m + e]; b[e] = acc1[4 * m + e]; }
      *(f32x4*)(base + 8 * m + 4 * hi) = a;
      *(f32x4*)(base + 32 + 8 * m + 4 * hi) = b;
    }
    if (!hi) { Mm[wq * 32 + l31] = m_run; Lm[wq * 32 + l31] = l_run; }
  }
  __syncthreads();
  if (!half) {
    const float m2 = Mm[wq * 32 + l31];
    const float l2 = Lm[wq * 32 + l31];
    const float mm = fmaxf(m_run, m2);
    const float e1 = exp2_fast(m_run - mm);
    const float e2 = exp2_fast(m2 - mm);
    const float inv = 1.0f / (l_run * e1 + l2 * e2);
    const float* base = Om + (wq * 32 + l31) * 68;
#pragma unroll
    for (int m = 0; m < 4; ++m) {
      f32x4 o2a = *(const f32x4*)(base + 8 * m + 4 * hi);
      f32x4 o2b = *(const f32x4*)(base + 32 + 8 * m + 4 * hi);
      f32x4 oa, ob;
#pragma unroll
      for (int e = 0; e < 4; ++e) {
        oa[e] = (acc0[4 * m + e] * e1 + o2a[e] * e2) * inv;
        ob[e] = (acc1[4 * m + e] * e1 + o2b[e] * e2) * inv;
      }
      *(f32x4*)&Oh[(size_t)qrow * Dn + 8 * m + 4 * hi] = oa;
      *(f32x4*)&Oh[(size_t)qrow * Dn + 32 + 8 * m + 4 * hi] = ob;
    }
  }
}

extern "C" void kernel_launch(void* const* d_in, const int* in_sizes, int n_in,
                              void* d_out, int out_size, void* d_ws, size_t ws_size,
                              hipStream_t stream) {
  const float* Q = (const float*)d_in[0];
  const float* K = (const float*)d_in[1];
  const float* V = (const float*)d_in[2];
  const float* M = (const float*)d_in[3];
  float* O = (float*)d_out;
  dim3 grid(Bn * Hn * (Sn / QB));  // 512
  sdpa_fa4<<<grid, dim3(512), 0, stream>>>(Q, K, V, M, O);
}